// Round 3
// baseline (2999.641 us; speedup 1.0000x reference)
//
#include <hip/hip_runtime.h>
#include <math.h>

#define NBATCH 4096
#define NH2 21
#define NK 77
#define NC 35
#define NIJ 441
#define Y_SIZE 33957
#define M_SIZE 5929
#define VOLOFF Y_SIZE          // vol[n] at out[VOLOFF + n] (temp, inside M region)
#define VSUM (Y_SIZE + 4096)   // volsum at out[VSUM] (temp, inside M region)
#define NSPLIT 8
#define NSLICE (NBATCH / NSPLIT)

#define SZ_OMEGA  (NBATCH * NH2 * NH2)   // 1,806,336
#define SZ_PHI    (NBATCH * NK * NC)     // 11,038,720
#define SZ_METRIC (NBATCH * 7 * 7)       // 200,704

// ---------------- compile-time wedge structure constants ----------------
// C[a,b,c] nonzero iff pair_a, pair_b, triple_c partition {0..6}; value = perm sign.
// Exactly 6 (a,b) terms per c.
struct WTab {
  int a[NC][6];
  int b[NC][6];
  int sg[NC][6];
};

constexpr WTab make_wtab() {
  WTab W{};
  int p0[21] = {}, p1[21] = {};
  int idx = 0;
  for (int x = 0; x < 7; ++x)
    for (int y = x + 1; y < 7; ++y) { p0[idx] = x; p1[idx] = y; ++idx; }
  int t0[35] = {}, t1[35] = {}, t2[35] = {};
  idx = 0;
  for (int x = 0; x < 7; ++x)
    for (int y = x + 1; y < 7; ++y)
      for (int z = y + 1; z < 7; ++z) { t0[idx] = x; t1[idx] = y; t2[idx] = z; ++idx; }
  int cnt[35] = {};
  for (int a = 0; a < 21; ++a)
    for (int b = 0; b < 21; ++b) {
      int pa0 = p0[a], pa1 = p1[a], pb0 = p0[b], pb1 = p1[b];
      if (pa0 == pb0 || pa0 == pb1 || pa1 == pb0 || pa1 == pb1) continue;
      bool used[7] = {};
      used[pa0] = true; used[pa1] = true; used[pb0] = true; used[pb1] = true;
      int tr[3] = {}; int k = 0;
      for (int x = 0; x < 7; ++x) if (!used[x]) tr[k++] = x;
      int c = -1;
      for (int cc = 0; cc < 35; ++cc)
        if (t0[cc] == tr[0] && t1[cc] == tr[1] && t2[cc] == tr[2]) { c = cc; break; }
      int perm[7] = {pa0, pa1, pb0, pb1, tr[0], tr[1], tr[2]};
      int inv = 0;
      for (int i = 0; i < 7; ++i)
        for (int j = i + 1; j < 7; ++j)
          if (perm[i] > perm[j]) ++inv;
      W.a[c][cnt[c]] = a; W.b[c][cnt[c]] = b; W.sg[c][cnt[c]] = (inv & 1) ? -1 : 1;
      ++cnt[c];
    }
  return W;
}

// ---------------- kernel A: vol[n] = sqrt(|det(metric_n)|), + sum ----------------
__global__ __launch_bounds__(256) void vol_kernel(const float* __restrict__ metric,
                                                  float* __restrict__ out) {
  const int n = blockIdx.x * 256 + threadIdx.x;
  double a[7][7];
#pragma unroll
  for (int r = 0; r < 7; ++r)
#pragma unroll
    for (int c = 0; c < 7; ++c) a[r][c] = (double)metric[n * 49 + r * 7 + c];

  double det = 1.0;
#pragma unroll
  for (int k = 0; k < 7; ++k) {
#pragma unroll
    for (int r = k + 1; r < 7; ++r) {   // bubble max |pivot| into row k
      bool sw = fabs(a[r][k]) > fabs(a[k][k]);
#pragma unroll
      for (int c = k; c < 7; ++c) {
        double u = a[k][c], v = a[r][c];
        a[k][c] = sw ? v : u;
        a[r][c] = sw ? u : v;
      }
    }
    det *= a[k][k];
    double inv = (a[k][k] != 0.0) ? 1.0 / a[k][k] : 0.0;
#pragma unroll
    for (int r = k + 1; r < 7; ++r) {
      double f = a[r][k] * inv;
#pragma unroll
      for (int c = k + 1; c < 7; ++c) a[r][c] -= f * a[k][c];
    }
  }
  float vol = (float)sqrt(fabs(det));
  out[VOLOFF + n] = vol;

  float s = vol;
#pragma unroll
  for (int off = 32; off > 0; off >>= 1) s += __shfl_down(s, off, 64);
  __shared__ float partial[4];
  const int lane = threadIdx.x & 63, wv = threadIdx.x >> 6;
  if (lane == 0) partial[wv] = s;
  __syncthreads();
  if (threadIdx.x == 0)
    atomicAdd(out + VSUM, partial[0] + partial[1] + partial[2] + partial[3]);
}

// ---------------- kernel B (BORING): Sraw[ij,k] partial over an n-slice ----------
// One thread per output element (ij,k); blockIdx.y selects the n-slice.
// No LDS, no tiling: straight global reads, fp64 accumulation, 1 atomicAdd.
__global__ __launch_bounds__(256) void yraw_kernel(const float* __restrict__ omega,
                                                   const float* __restrict__ Phi,
                                                   float* __restrict__ out) {
  constexpr WTab W = make_wtab();   // constexpr local -> guaranteed compile-time fold

  const int e = blockIdx.x * 256 + threadIdx.x;
  if (e >= Y_SIZE) return;
  const int ij = e / NK;
  const int k = e % NK;
  const int i = ij / NH2;
  const int j = ij % NH2;
  const int n0 = blockIdx.y * NSLICE;

  double accd = 0.0;
  for (int n = n0; n < n0 + NSLICE; ++n) {
    const float vn = out[VOLOFF + n];
    const float* oi = omega + n * 441 + i * 21;
    const float* oj = omega + n * 441 + j * 21;
    const float* ph = Phi + n * 2695 + k * 35;
    float wi[21], wj[21];
#pragma unroll
    for (int a = 0; a < 21; ++a) { wi[a] = oi[a]; wj[a] = oj[a]; }

    float inner = 0.0f;
#pragma unroll
    for (int c = 0; c < 35; ++c) {
      float d = 0.0f;
#pragma unroll
      for (int u = 0; u < 6; ++u) {
        const int A = W.a[c][u];
        const int B = W.b[c][u];
        d = fmaf((W.sg[c][u] > 0) ? wi[A] : -wi[A], wj[B], d);
      }
      inner = fmaf(d, ph[c], inner);
    }
    accd += (double)(vn * inner);
  }
  atomicAdd(&out[e], (float)accd);
}

// ---------------- kernel C1: Y = sign * Sraw / volsum, in place ----------------
__global__ __launch_bounds__(256) void finalize_y(float* __restrict__ out) {
  const int e = blockIdx.x * 256 + threadIdx.x;
  if (e >= Y_SIZE) return;
  const float inv = 1.0f / out[VSUM];
  const int ij = e / NK;
  const int i = ij / NH2, j = ij % NH2;
  const float v = out[e] * inv;
  out[e] = (j >= i) ? v : -v;
}

// ---------------- kernel C2: M[k,l] = sum_ij Y_ij,k Y_ij,l (signs cancel) --------
__global__ __launch_bounds__(256) void gram_kernel(const float* __restrict__ Y,
                                                   float* __restrict__ Mout) {
  const int e = blockIdx.x * 256 + threadIdx.x;
  if (e >= M_SIZE) return;
  const int k = e / NK, l = e % NK;
  float acc = 0.0f;
  for (int ij = 0; ij < NIJ; ++ij)
    acc = fmaf(Y[ij * NK + k], Y[ij * NK + l], acc);
  Mout[e] = acc;
}

// ---------------- kernel D: eigvalsh(M), descending ----------------
__device__ __forceinline__ double blk_reduce_d(double v, double* red, double* bc) {
  const int t = threadIdx.x;
#pragma unroll
  for (int off = 32; off > 0; off >>= 1) v += __shfl_down(v, off, 64);
  __syncthreads();
  if ((t & 63) == 0) red[t >> 6] = v;
  __syncthreads();
  if (t == 0) *bc = red[0] + red[1] + red[2] + red[3];
  __syncthreads();
  return *bc;
}

__global__ __launch_bounds__(256) void eig_kernel(const float* __restrict__ Min,
                                                  float* __restrict__ eout) {
  __shared__ double A[77][78];
  __shared__ double red[4];
  __shared__ double bcast;
  __shared__ double vsh[77], psh[77], wsh[77], esh[77];
  __shared__ float df[77], e2f[77];
  __shared__ float glo, ghi;
  const int t = threadIdx.x;

  for (int f = t; f < M_SIZE; f += 256) A[f / 77][f % 77] = (double)Min[f];
  __syncthreads();

  // Householder tridiagonalization (fp64, rank-2 update)
  for (int k = 0; k < 75; ++k) {
    const int lo = k + 1;
    const int m = 76 - k;

    double part = 0.0;
    for (int i = lo + t; i <= 76; i += 256) part += A[i][k] * A[i][k];
    const double sigma2 = blk_reduce_d(part, red, &bcast);
    const double x1 = A[lo][k];

    if (sigma2 < 1e-300) {
      if (t == 0) esh[k] = 0.0;
      __syncthreads();
      continue;
    }
    const double sigma = sqrt(sigma2);
    const double alpha = (x1 >= 0.0) ? -sigma : sigma;
    const double beta = 1.0 / (sigma2 - alpha * x1);  // = 2 / (v^T v)

    for (int i = lo + t; i <= 76; i += 256) vsh[i] = (i == lo) ? (x1 - alpha) : A[i][k];
    if (t == 0) esh[k] = alpha;
    __syncthreads();

    for (int i = lo + t; i <= 76; i += 256) {
      double s = 0.0;
      for (int j = lo; j <= 76; ++j) s += A[i][j] * vsh[j];
      psh[i] = beta * s;
    }
    __syncthreads();

    double part2 = 0.0;
    for (int i = lo + t; i <= 76; i += 256) part2 += psh[i] * vsh[i];
    const double K = blk_reduce_d(part2, red, &bcast);
    const double hb = 0.5 * beta * K;
    for (int i = lo + t; i <= 76; i += 256) wsh[i] = psh[i] - hb * vsh[i];
    __syncthreads();

    const int tot = m * m;
    for (int q = t; q < tot; q += 256) {
      const int ii = lo + q / m, jj = lo + q % m;
      A[ii][jj] -= vsh[ii] * wsh[jj] + wsh[ii] * vsh[jj];
    }
    __syncthreads();
  }

  if (t < 77) df[t] = (float)A[t][t];
  if (t == 0) esh[75] = A[76][75];
  __syncthreads();
  if (t < 76) { float ev = (float)esh[t]; e2f[t] = ev * ev; }
  __syncthreads();

  if (t == 0) {  // Gershgorin bounds
    float lo_ = 1e30f, hi_ = -1e30f;
    for (int i = 0; i < 77; ++i) {
      float r = ((i > 0) ? fabsf((float)esh[i - 1]) : 0.0f) +
                ((i < 76) ? fabsf((float)esh[i]) : 0.0f);
      lo_ = fminf(lo_, df[i] - r);
      hi_ = fmaxf(hi_, df[i] + r);
    }
    const float span = hi_ - lo_;
    glo = lo_ - 0.001f * span - 1e-6f;
    ghi = hi_ + 0.001f * span + 1e-6f;
  }
  __syncthreads();

  if (t < 77) {  // bisection via Sturm count
    float lo = glo, hi = ghi;
    for (int it = 0; it < 48; ++it) {
      const float mid = 0.5f * (lo + hi);
      float q = df[0] - mid;
      int cnt = (q < 0.0f);
      for (int i = 1; i < 77; ++i) {
        if (fabsf(q) < 1e-30f) q = -1e-30f;
        q = df[i] - mid - e2f[i - 1] / q;
        cnt += (q < 0.0f);
      }
      if (cnt > t) hi = mid; else lo = mid;
    }
    eout[76 - t] = 0.5f * (lo + hi);  // descending
  }
}

// ---------------- launch ----------------
extern "C" void kernel_launch(void* const* d_in, const int* in_sizes, int n_in,
                              void* d_out, int out_size, void* d_ws, size_t ws_size,
                              hipStream_t stream) {
  // Defensive: select inputs BY ELEMENT COUNT (all three are distinct sizes),
  // falling back to documented dict order if sizes don't match.
  const float* omega  = (const float*)d_in[0];
  const float* Phi    = (const float*)d_in[1];
  const float* metric = (const float*)d_in[2];
  for (int q = 0; q < n_in && q < 3; ++q) {
    if (in_sizes[q] == SZ_OMEGA)  omega  = (const float*)d_in[q];
    else if (in_sizes[q] == SZ_PHI)    Phi    = (const float*)d_in[q];
    else if (in_sizes[q] == SZ_METRIC) metric = (const float*)d_in[q];
  }

  float* out = (float*)d_out;

  // All scratch lives inside d_out (d_ws unused):
  //   out[0 .. Y_SIZE)            : Sraw accumulator -> finalized Y
  //   out[VOLOFF .. VOLOFF+4096)  : vol[n] (temp, overwritten by gram's M)
  //   out[VSUM]                   : volsum (temp, overwritten by gram's M)
  hipMemsetAsync(d_out, 0, (size_t)out_size * sizeof(float), stream);

  hipLaunchKernelGGL(vol_kernel, dim3(NBATCH / 256), dim3(256), 0, stream, metric, out);
  hipLaunchKernelGGL(yraw_kernel, dim3((Y_SIZE + 255) / 256, NSPLIT), dim3(256), 0,
                     stream, omega, Phi, out);
  hipLaunchKernelGGL(finalize_y, dim3((Y_SIZE + 255) / 256), dim3(256), 0, stream, out);
  hipLaunchKernelGGL(gram_kernel, dim3((M_SIZE + 255) / 256), dim3(256), 0, stream,
                     out, out + Y_SIZE);
  hipLaunchKernelGGL(eig_kernel, dim3(1), dim3(256), 0, stream,
                     out + Y_SIZE, out + Y_SIZE + M_SIZE);
}

// Round 4
// 1138.925 us; speedup vs baseline: 2.6337x; 2.6337x over previous
//
#include <hip/hip_runtime.h>
#include <math.h>

#define NBATCH 4096
#define NH2 21
#define NK 77
#define NC 35
#define NIJ 441
#define Y_SIZE 33957
#define M_SIZE 5929
#define VOLOFF Y_SIZE          // vol[n] at out[VOLOFF + n] (temp, inside M region)
#define VSUM (Y_SIZE + 4096)   // volsum at out[VSUM] (temp, inside M region)
#define KT 11                  // k-tile: 7 tiles cover 77
#define CHUNK 32               // n per block
#define NCHUNK (NBATCH / CHUNK)

#define SZ_OMEGA  (NBATCH * NH2 * NH2)   // 1,806,336
#define SZ_PHI    (NBATCH * NK * NC)     // 11,038,720
#define SZ_METRIC (NBATCH * 7 * 7)       // 200,704

// ---------------- compile-time wedge structure constants ----------------
// C[a,b,c] nonzero iff pair_a, pair_b, triple_c partition {0..6}; value = perm sign.
// Exactly 6 (a,b) terms per c. NOTE: must be materialized as a constexpr LOCAL
// inside each kernel (round-3 finding: __device__ constexpr global risked
// zero-init; constexpr local is guaranteed compile-time folded).
struct WTab {
  int a[NC][6];
  int b[NC][6];
  int sg[NC][6];
};

constexpr WTab make_wtab() {
  WTab W{};
  int p0[21] = {}, p1[21] = {};
  int idx = 0;
  for (int x = 0; x < 7; ++x)
    for (int y = x + 1; y < 7; ++y) { p0[idx] = x; p1[idx] = y; ++idx; }
  int t0[35] = {}, t1[35] = {}, t2[35] = {};
  idx = 0;
  for (int x = 0; x < 7; ++x)
    for (int y = x + 1; y < 7; ++y)
      for (int z = y + 1; z < 7; ++z) { t0[idx] = x; t1[idx] = y; t2[idx] = z; ++idx; }
  int cnt[35] = {};
  for (int a = 0; a < 21; ++a)
    for (int b = 0; b < 21; ++b) {
      int pa0 = p0[a], pa1 = p1[a], pb0 = p0[b], pb1 = p1[b];
      if (pa0 == pb0 || pa0 == pb1 || pa1 == pb0 || pa1 == pb1) continue;
      bool used[7] = {};
      used[pa0] = true; used[pa1] = true; used[pb0] = true; used[pb1] = true;
      int tr[3] = {}; int k = 0;
      for (int x = 0; x < 7; ++x) if (!used[x]) tr[k++] = x;
      int c = -1;
      for (int cc = 0; cc < 35; ++cc)
        if (t0[cc] == tr[0] && t1[cc] == tr[1] && t2[cc] == tr[2]) { c = cc; break; }
      int perm[7] = {pa0, pa1, pb0, pb1, tr[0], tr[1], tr[2]};
      int inv = 0;
      for (int i = 0; i < 7; ++i)
        for (int j = i + 1; j < 7; ++j)
          if (perm[i] > perm[j]) ++inv;
      W.a[c][cnt[c]] = a; W.b[c][cnt[c]] = b; W.sg[c][cnt[c]] = (inv & 1) ? -1 : 1;
      ++cnt[c];
    }
  return W;
}

// ---------------- kernel A: vol[n] = sqrt(|det(metric_n)|), + sum ----------------
__global__ __launch_bounds__(256) void vol_kernel(const float* __restrict__ metric,
                                                  float* __restrict__ out) {
  const int n = blockIdx.x * 256 + threadIdx.x;
  double a[7][7];
#pragma unroll
  for (int r = 0; r < 7; ++r)
#pragma unroll
    for (int c = 0; c < 7; ++c) a[r][c] = (double)metric[n * 49 + r * 7 + c];

  double det = 1.0;
#pragma unroll
  for (int k = 0; k < 7; ++k) {
#pragma unroll
    for (int r = k + 1; r < 7; ++r) {   // bubble max |pivot| into row k
      bool sw = fabs(a[r][k]) > fabs(a[k][k]);
#pragma unroll
      for (int c = k; c < 7; ++c) {
        double u = a[k][c], v = a[r][c];
        a[k][c] = sw ? v : u;
        a[r][c] = sw ? u : v;
      }
    }
    det *= a[k][k];
    double inv = (a[k][k] != 0.0) ? 1.0 / a[k][k] : 0.0;
#pragma unroll
    for (int r = k + 1; r < 7; ++r) {
      double f = a[r][k] * inv;
#pragma unroll
      for (int c = k + 1; c < 7; ++c) a[r][c] -= f * a[k][c];
    }
  }
  float vol = (float)sqrt(fabs(det));
  out[VOLOFF + n] = vol;

  float s = vol;
#pragma unroll
  for (int off = 32; off > 0; off >>= 1) s += __shfl_down(s, off, 64);
  __shared__ float partial[4];
  const int lane = threadIdx.x & 63, wv = threadIdx.x >> 6;
  if (lane == 0) partial[wv] = s;
  __syncthreads();
  if (threadIdx.x == 0)
    atomicAdd(out + VSUM, partial[0] + partial[1] + partial[2] + partial[3]);
}

// ---------------- kernel B: tiled contract, register accumulators ----------------
// grid (7 k-tiles, 128 n-chunks) x 256 threads. Thread owns ij0=t, ij1=t+256.
// Per n: stage omega(441) + vol-scaled Phi k-tile(385) into LDS; compute
// D[c] per owned ij from the 6-term wedge table (pure reg FMAs); accumulate
// acc[kk] += dot(D, pw_row_kk) with each pw float4 read ONCE and shared by
// both owned ij's. Flush via atomicAdd (128 chunk-blocks contend per element).
__global__ __launch_bounds__(256) void contract_kernel(const float* __restrict__ omega,
                                                       const float* __restrict__ Phi,
                                                       float* __restrict__ out) {
  constexpr WTab W = make_wtab();
  __shared__ __align__(16) float lds_om[NH2 * 24];  // rows padded to 24 floats
  __shared__ __align__(16) float lds_pw[KT * 36];   // rows padded to 36 floats

  const int t = threadIdx.x;
  const int k0 = blockIdx.x * KT;
  const int n0 = blockIdx.y * CHUNK;

  const int i0 = t / 21, j0 = t % 21;
  const int ij1 = t + 256;
  const int i1 = ij1 / 21, j1 = ij1 % 21;
  const bool has1 = (ij1 < NIJ);

  if (t < KT) lds_pw[t * 36 + 35] = 0.0f;  // pad col, never overwritten

  float acc0[KT], acc1[KT];
#pragma unroll
  for (int kk = 0; kk < KT; ++kk) { acc0[kk] = 0.0f; acc1[kk] = 0.0f; }

  for (int n = n0; n < n0 + CHUNK; ++n) {
    const float vn = out[VOLOFF + n];
    const float* om = omega + n * 441;
    const float* ph = Phi + n * 2695 + k0 * 35;

    __syncthreads();  // previous iteration's consumers done
    {
      int f = t;
      lds_om[(f / 21) * 24 + (f % 21)] = om[f];
      f = t + 256;
      if (f < 441) lds_om[(f / 21) * 24 + (f % 21)] = om[f];
      lds_pw[(t / 35) * 36 + (t % 35)] = vn * ph[t];
      f = t + 256;
      if (f < 385) lds_pw[(f / 35) * 36 + (f % 35)] = vn * ph[f];
    }
    __syncthreads();

    // D for ij0 and (maybe) ij1 — wedge table folded at compile time
    float d0[36], d1[36];
    {
      float wi[21], wj[21];
      const float* oi = lds_om + i0 * 24;
      const float* oj = lds_om + j0 * 24;
#pragma unroll
      for (int a = 0; a < 20; a += 4) {
        float4 v = *(const float4*)(oi + a);
        wi[a] = v.x; wi[a + 1] = v.y; wi[a + 2] = v.z; wi[a + 3] = v.w;
        float4 u = *(const float4*)(oj + a);
        wj[a] = u.x; wj[a + 1] = u.y; wj[a + 2] = u.z; wj[a + 3] = u.w;
      }
      wi[20] = oi[20]; wj[20] = oj[20];
#pragma unroll
      for (int c = 0; c < 35; ++c) {
        float d = 0.0f;
#pragma unroll
        for (int u = 0; u < 6; ++u)
          d = fmaf((W.sg[c][u] > 0) ? wi[W.a[c][u]] : -wi[W.a[c][u]], wj[W.b[c][u]], d);
        d0[c] = d;
      }
      d0[35] = 0.0f;
    }
    if (has1) {
      float wi[21], wj[21];
      const float* oi = lds_om + i1 * 24;
      const float* oj = lds_om + j1 * 24;
#pragma unroll
      for (int a = 0; a < 20; a += 4) {
        float4 v = *(const float4*)(oi + a);
        wi[a] = v.x; wi[a + 1] = v.y; wi[a + 2] = v.z; wi[a + 3] = v.w;
        float4 u = *(const float4*)(oj + a);
        wj[a] = u.x; wj[a + 1] = u.y; wj[a + 2] = u.z; wj[a + 3] = u.w;
      }
      wi[20] = oi[20]; wj[20] = oj[20];
#pragma unroll
      for (int c = 0; c < 35; ++c) {
        float d = 0.0f;
#pragma unroll
        for (int u = 0; u < 6; ++u)
          d = fmaf((W.sg[c][u] > 0) ? wi[W.a[c][u]] : -wi[W.a[c][u]], wj[W.b[c][u]], d);
        d1[c] = d;
      }
      d1[35] = 0.0f;
    } else {
#pragma unroll
      for (int c = 0; c < 36; ++c) d1[c] = 0.0f;
    }

    // acc[kk] += dot(d, pw_row_kk); each pw float4 read once, shared by d0/d1
#pragma unroll
    for (int kk = 0; kk < KT; ++kk) {
      const float* pw = lds_pw + kk * 36;  // wave-uniform address -> broadcast
      float a0 = 0.f, a1 = 0.f, a2 = 0.f, a3 = 0.f;
      float b0 = 0.f, b1 = 0.f, b2 = 0.f, b3 = 0.f;
#pragma unroll
      for (int c = 0; c < 36; c += 4) {
        float4 p = *(const float4*)(pw + c);
        a0 = fmaf(d0[c + 0], p.x, a0);
        a1 = fmaf(d0[c + 1], p.y, a1);
        a2 = fmaf(d0[c + 2], p.z, a2);
        a3 = fmaf(d0[c + 3], p.w, a3);
        b0 = fmaf(d1[c + 0], p.x, b0);
        b1 = fmaf(d1[c + 1], p.y, b1);
        b2 = fmaf(d1[c + 2], p.z, b2);
        b3 = fmaf(d1[c + 3], p.w, b3);
      }
      acc0[kk] += (a0 + a1) + (a2 + a3);
      acc1[kk] += (b0 + b1) + (b2 + b3);
    }
  }

  // flush: 128 chunk-blocks accumulate into Sraw (= out Y region)
#pragma unroll
  for (int kk = 0; kk < KT; ++kk)
    atomicAdd(&out[t * 77 + k0 + kk], acc0[kk]);
  if (has1) {
#pragma unroll
    for (int kk = 0; kk < KT; ++kk)
      atomicAdd(&out[ij1 * 77 + k0 + kk], acc1[kk]);
  }
}

// ---------------- kernel C1: Y = sign * Sraw / volsum, in place ----------------
__global__ __launch_bounds__(256) void finalize_y(float* __restrict__ out) {
  const int e = blockIdx.x * 256 + threadIdx.x;
  if (e >= Y_SIZE) return;
  const float inv = 1.0f / out[VSUM];
  const int ij = e / NK;
  const int i = ij / NH2, j = ij % NH2;
  const float v = out[e] * inv;
  out[e] = (j >= i) ? v : -v;
}

// ---------------- kernel C2: M[k,l] = sum_ij Y_ij,k Y_ij,l (signs cancel) --------
__global__ __launch_bounds__(256) void gram_kernel(const float* __restrict__ Y,
                                                   float* __restrict__ Mout) {
  const int e = blockIdx.x * 256 + threadIdx.x;
  if (e >= M_SIZE) return;
  const int k = e / NK, l = e % NK;
  float acc = 0.0f;
  for (int ij = 0; ij < NIJ; ++ij)
    acc = fmaf(Y[ij * NK + k], Y[ij * NK + l], acc);
  Mout[e] = acc;
}

// ---------------- kernel D: eigvalsh(M), descending ----------------
__device__ __forceinline__ double blk_reduce_d(double v, double* red, double* bc) {
  const int t = threadIdx.x;
#pragma unroll
  for (int off = 32; off > 0; off >>= 1) v += __shfl_down(v, off, 64);
  __syncthreads();
  if ((t & 63) == 0) red[t >> 6] = v;
  __syncthreads();
  if (t == 0) *bc = red[0] + red[1] + red[2] + red[3];
  __syncthreads();
  return *bc;
}

__global__ __launch_bounds__(256) void eig_kernel(const float* __restrict__ Min,
                                                  float* __restrict__ eout) {
  __shared__ double A[77][78];
  __shared__ double red[4];
  __shared__ double bcast;
  __shared__ double vsh[77], psh[77], wsh[77], esh[77];
  __shared__ float df[77], e2f[77];
  __shared__ float glo, ghi;
  const int t = threadIdx.x;

  for (int f = t; f < M_SIZE; f += 256) A[f / 77][f % 77] = (double)Min[f];
  __syncthreads();

  // Householder tridiagonalization (fp64, rank-2 update)
  for (int k = 0; k < 75; ++k) {
    const int lo = k + 1;
    const int m = 76 - k;

    double part = 0.0;
    for (int i = lo + t; i <= 76; i += 256) part += A[i][k] * A[i][k];
    const double sigma2 = blk_reduce_d(part, red, &bcast);
    const double x1 = A[lo][k];

    if (sigma2 < 1e-300) {
      if (t == 0) esh[k] = 0.0;
      __syncthreads();
      continue;
    }
    const double sigma = sqrt(sigma2);
    const double alpha = (x1 >= 0.0) ? -sigma : sigma;
    const double beta = 1.0 / (sigma2 - alpha * x1);  // = 2 / (v^T v)

    for (int i = lo + t; i <= 76; i += 256) vsh[i] = (i == lo) ? (x1 - alpha) : A[i][k];
    if (t == 0) esh[k] = alpha;
    __syncthreads();

    for (int i = lo + t; i <= 76; i += 256) {
      double s = 0.0;
      for (int j = lo; j <= 76; ++j) s += A[i][j] * vsh[j];
      psh[i] = beta * s;
    }
    __syncthreads();

    double part2 = 0.0;
    for (int i = lo + t; i <= 76; i += 256) part2 += psh[i] * vsh[i];
    const double K = blk_reduce_d(part2, red, &bcast);
    const double hb = 0.5 * beta * K;
    for (int i = lo + t; i <= 76; i += 256) wsh[i] = psh[i] - hb * vsh[i];
    __syncthreads();

    const int tot = m * m;
    for (int q = t; q < tot; q += 256) {
      const int ii = lo + q / m, jj = lo + q % m;
      A[ii][jj] -= vsh[ii] * wsh[jj] + wsh[ii] * vsh[jj];
    }
    __syncthreads();
  }

  if (t < 77) df[t] = (float)A[t][t];
  if (t == 0) esh[75] = A[76][75];
  __syncthreads();
  if (t < 76) { float ev = (float)esh[t]; e2f[t] = ev * ev; }
  __syncthreads();

  if (t == 0) {  // Gershgorin bounds
    float lo_ = 1e30f, hi_ = -1e30f;
    for (int i = 0; i < 77; ++i) {
      float r = ((i > 0) ? fabsf((float)esh[i - 1]) : 0.0f) +
                ((i < 76) ? fabsf((float)esh[i]) : 0.0f);
      lo_ = fminf(lo_, df[i] - r);
      hi_ = fmaxf(hi_, df[i] + r);
    }
    const float span = hi_ - lo_;
    glo = lo_ - 0.001f * span - 1e-6f;
    ghi = hi_ + 0.001f * span + 1e-6f;
  }
  __syncthreads();

  if (t < 77) {  // bisection via Sturm count
    float lo = glo, hi = ghi;
    for (int it = 0; it < 48; ++it) {
      const float mid = 0.5f * (lo + hi);
      float q = df[0] - mid;
      int cnt = (q < 0.0f);
      for (int i = 1; i < 77; ++i) {
        if (fabsf(q) < 1e-30f) q = -1e-30f;
        q = df[i] - mid - e2f[i - 1] / q;
        cnt += (q < 0.0f);
      }
      if (cnt > t) hi = mid; else lo = mid;
    }
    eout[76 - t] = 0.5f * (lo + hi);  // descending
  }
}

// ---------------- launch ----------------
extern "C" void kernel_launch(void* const* d_in, const int* in_sizes, int n_in,
                              void* d_out, int out_size, void* d_ws, size_t ws_size,
                              hipStream_t stream) {
  // Inputs selected BY ELEMENT COUNT (all distinct), fallback to dict order.
  const float* omega  = (const float*)d_in[0];
  const float* Phi    = (const float*)d_in[1];
  const float* metric = (const float*)d_in[2];
  for (int q = 0; q < n_in && q < 3; ++q) {
    if (in_sizes[q] == SZ_OMEGA)       omega  = (const float*)d_in[q];
    else if (in_sizes[q] == SZ_PHI)    Phi    = (const float*)d_in[q];
    else if (in_sizes[q] == SZ_METRIC) metric = (const float*)d_in[q];
  }

  float* out = (float*)d_out;

  // All scratch lives inside d_out (d_ws unused):
  //   out[0 .. Y_SIZE)            : Sraw accumulator -> finalized Y
  //   out[VOLOFF .. VOLOFF+4096)  : vol[n] (temp, overwritten by gram's M)
  //   out[VSUM]                   : volsum (temp, overwritten by gram's M)
  hipMemsetAsync(d_out, 0, (size_t)out_size * sizeof(float), stream);

  hipLaunchKernelGGL(vol_kernel, dim3(NBATCH / 256), dim3(256), 0, stream, metric, out);
  hipLaunchKernelGGL(contract_kernel, dim3(7, NCHUNK), dim3(256), 0, stream,
                     omega, Phi, out);
  hipLaunchKernelGGL(finalize_y, dim3((Y_SIZE + 255) / 256), dim3(256), 0, stream, out);
  hipLaunchKernelGGL(gram_kernel, dim3((M_SIZE + 255) / 256), dim3(256), 0, stream,
                     out, out + Y_SIZE);
  hipLaunchKernelGGL(eig_kernel, dim3(1), dim3(256), 0, stream,
                     out + Y_SIZE, out + Y_SIZE + M_SIZE);
}